// Round 3
// baseline (1415.753 us; speedup 1.0000x reference)
//
#include <hip/hip_runtime.h>

typedef __bf16 v8bf __attribute__((ext_vector_type(8)));
typedef float  v16f __attribute__((ext_vector_type(16)));
typedef float  f4   __attribute__((ext_vector_type(4)));
typedef unsigned int uint;
typedef unsigned short ushort;
typedef uint   v4u  __attribute__((ext_vector_type(4)));
typedef uint   v2u  __attribute__((ext_vector_type(2)));

#define GLAS(p) ((const __attribute__((address_space(1))) void*)(p))
#define LDAS(p) ((__attribute__((address_space(3))) void*)(p))

__device__ __forceinline__ ushort f32_to_bf16(float f) {
    uint u = __builtin_bit_cast(uint, f);
    uint r = u + 0x7FFFu + ((u >> 16) & 1u);   // RNE; inputs finite
    return (ushort)(r >> 16);
}
__device__ __forceinline__ float bflo(uint v) { return __builtin_bit_cast(float, v << 16); }
__device__ __forceinline__ float bfhi(uint v) { return __builtin_bit_cast(float, v & 0xFFFF0000u); }

// ---------------- fused BN1 column stats + fp32->bf16 convert ----------------
__global__ void colstats_cvt(const float* __restrict__ x, ushort* __restrict__ xb,
                             float* __restrict__ sum, float* __restrict__ ssum,
                             int ncols, int rows) {
    int c4 = blockIdx.x * blockDim.x + threadIdx.x;   // column quad index
    int q = ncols >> 2;
    size_t base = (size_t)blockIdx.y * rows * q + c4;
    const f4* x4 = (const f4*)x;
    v2u* o = (v2u*)xb;
    f4 s = {0.f, 0.f, 0.f, 0.f}, qq = {0.f, 0.f, 0.f, 0.f};
#pragma unroll 4
    for (int r = 0; r < rows; ++r) {
        f4 v = x4[base + (size_t)r * q];
        s += v; qq += v * v;
        union { ushort us[4]; v2u u; } p;
        p.us[0] = f32_to_bf16(v.x); p.us[1] = f32_to_bf16(v.y);
        p.us[2] = f32_to_bf16(v.z); p.us[3] = f32_to_bf16(v.w);
        o[base + (size_t)r * q] = p.u;
    }
    atomicAdd(&sum[4 * c4 + 0], s.x);  atomicAdd(&ssum[4 * c4 + 0], qq.x);
    atomicAdd(&sum[4 * c4 + 1], s.y);  atomicAdd(&ssum[4 * c4 + 1], qq.y);
    atomicAdd(&sum[4 * c4 + 2], s.z);  atomicAdd(&ssum[4 * c4 + 2], qq.z);
    atomicAdd(&sum[4 * c4 + 3], s.w);  atomicAdd(&ssum[4 * c4 + 3], qq.w);
}

__global__ void colstats_bf16(const ushort* __restrict__ h, float* __restrict__ sum,
                              float* __restrict__ ssum, int ncols, int rows) {
    int cp = blockIdx.x * blockDim.x + threadIdx.x;   // column pair
    int half = ncols >> 1;
    const uint* h32 = (const uint*)h;
    size_t base = (size_t)blockIdx.y * rows * half + cp;
    float s0 = 0.f, q0 = 0.f, s1 = 0.f, q1 = 0.f;
#pragma unroll 4
    for (int r = 0; r < rows; ++r) {
        uint v = h32[base + (size_t)r * half];
        float a = bflo(v), b = bfhi(v);
        s0 += a; q0 += a * a;
        s1 += b; q1 += b * b;
    }
    atomicAdd(&sum[2 * cp], s0);  atomicAdd(&ssum[2 * cp], q0);
    atomicAdd(&sum[2 * cp + 1], s1); atomicAdd(&ssum[2 * cp + 1], q1);
}

__global__ void bn_finalize(const float* __restrict__ sum, const float* __restrict__ ssum,
                            const float* __restrict__ g, const float* __restrict__ b,
                            float* __restrict__ s, float* __restrict__ t, float invN) {
    int c = blockIdx.x * blockDim.x + threadIdx.x;
    float m = sum[c] * invN;
    float var = fmaxf(ssum[c] * invN - m * m, 0.f);
    float rs = rsqrtf(var + 1e-5f);
    float sc = rs * g[c];
    s[c] = sc;
    t[c] = b[c] - m * sc;
}

// ---------------- fold BN scale/shift into weights ----------------
__global__ void fold_w(const float* __restrict__ W, const float* __restrict__ bias,
                       const float* __restrict__ s, const float* __restrict__ t,
                       ushort* __restrict__ Wp, float* __restrict__ bp, int K) {
    int j = blockIdx.x, tx = threadIdx.x;
    const f4* row = (const f4*)(W + (size_t)j * K);
    const f4* s4 = (const f4*)s;
    const f4* t4 = (const f4*)t;
    v2u* orow = (v2u*)(Wp + (size_t)j * K);
    float part = 0.f;
    int K4 = K >> 2;
    for (int k = tx; k < K4; k += 256) {
        f4 v = row[k], sv = s4[k], tv = t4[k];
        part += v.x * tv.x + v.y * tv.y + v.z * tv.z + v.w * tv.w;
        union { ushort us[4]; v2u u; } o;
        o.us[0] = f32_to_bf16(v.x * sv.x);
        o.us[1] = f32_to_bf16(v.y * sv.y);
        o.us[2] = f32_to_bf16(v.z * sv.z);
        o.us[3] = f32_to_bf16(v.w * sv.w);
        orow[k] = o.u;
    }
    __shared__ float red[256];
    red[tx] = part;
    __syncthreads();
    for (int off = 128; off > 0; off >>= 1) {
        if (tx < off) red[tx] += red[tx + off];
        __syncthreads();
    }
    if (tx == 0) bp[j] = bias[j] + red[0];
}

// ---------------- 256x256 8-phase bf16 MFMA GEMM (B^T layout) ----------------
// C[m,n] = sum_k A[m,k]*B[n,k] (+ epilogue).  BM=BN=256, BK=64, 512 threads =
// 8 waves (2M x 4N); each wave owns 128x64 via 4x2 frags of 32x32x16 MFMA.
// LDS: 2 dbuf x (A,B) x 256x64 bf16 = 128 KiB. Granule (row,c) (granule = 8
// bf16 = 16B) lives at physical granule row*8 + (c ^ (row&7)) -> fragment
// ds_read_b128s conflict-free per 8-lane group.  Staged via global_load_lds
// width 16 with pre-swizzled global source (lds dest stays linear).
// Per K-tile: 4 quadrant phases (i,j) in {(0,0),(0,1),(1,0),(1,1)}:
//   12 ds_read_b128 || stage one 16KB half-tile (2 global_load_lds/wave)
//   s_barrier; lgkmcnt(0); setprio(1); 8 MFMA; setprio(0); [vmcnt(4)]; s_barrier
// Staging runs 1.5 tiles ahead into just-freed regions:
//   ph0: (t+1).A-h1 -> nxt   ph1: (t+1).B-h1 -> nxt
//   ph2: (t+2).A-h0 -> cur   ph3: (t+2).B-h0 -> cur
// Boundary vmcnt(4) at ph3 => tile t+1 (8 oldest loads) landed; 2 half-tiles
// of tile t+2 stay in flight across the barrier (never drain to 0 == T4).
// 32x32x16 A/B frag: m(or n)=lane&31, k=(lane>>5)*8+j.
// 32x32 C/D: col=lane&31, row=(reg&3)+8*(reg>>2)+4*(lane>>5)   [m74/m101]
// EPI=0: out bf16 = relu(acc + bias[col]);  EPI=1: f32 = acc+bias+beta*Y.

__device__ __forceinline__ void stage_A(const ushort* __restrict__ Mat, ushort* dst,
                                        int K, int k0, int ihalf, int wave, int lane) {
    const int rs = lane >> 3;
    const int gc = (lane & 7) ^ rs;
    const int rb0 = ihalf * 64 + wave * 8;
    const int rb1 = rb0 + 128;
    const ushort* s0 = Mat + (size_t)(rb0 + rs) * K + k0 + gc * 8;
    const ushort* s1 = Mat + (size_t)(rb1 + rs) * K + k0 + gc * 8;
    __builtin_amdgcn_global_load_lds(GLAS(s0), LDAS(dst + rb0 * 64), 16, 0, 0);
    __builtin_amdgcn_global_load_lds(GLAS(s1), LDAS(dst + rb1 * 64), 16, 0, 0);
}
__device__ __forceinline__ void stage_B(const ushort* __restrict__ Mat, ushort* dst,
                                        int K, int k0, int jhalf, int wave, int lane) {
    const int rs = lane >> 3;
    const int gc = (lane & 7) ^ rs;
    const int rb0 = (wave >> 2) * 64 + jhalf * 32 + (wave & 3) * 8;
    const int rb1 = rb0 + 128;
    const ushort* s0 = Mat + (size_t)(rb0 + rs) * K + k0 + gc * 8;
    const ushort* s1 = Mat + (size_t)(rb1 + rs) * K + k0 + gc * 8;
    __builtin_amdgcn_global_load_lds(GLAS(s0), LDAS(dst + rb0 * 64), 16, 0, 0);
    __builtin_amdgcn_global_load_lds(GLAS(s1), LDAS(dst + rb1 * 64), 16, 0, 0);
}

#define PHASE(I, J, STAGE_STMT, WAIT_STMT)                                          \
    {                                                                               \
        v8bf a[2][4], b[4];                                                         \
        _Pragma("unroll") for (int m2 = 0; m2 < 2; ++m2)                            \
            _Pragma("unroll") for (int ks = 0; ks < 4; ++ks)                        \
                a[m2][ks] = __builtin_bit_cast(                                     \
                    v8bf, *(const v4u*)((const char*)curA + offA[I][m2][ks]));      \
        _Pragma("unroll") for (int ks = 0; ks < 4; ++ks)                            \
            b[ks] = __builtin_bit_cast(                                             \
                v8bf, *(const v4u*)((const char*)curB + offB[J][ks]));              \
        STAGE_STMT;                                                                 \
        __builtin_amdgcn_s_barrier();                                               \
        asm volatile("s_waitcnt lgkmcnt(0)" ::: "memory");                          \
        __builtin_amdgcn_sched_barrier(0);                                          \
        __builtin_amdgcn_s_setprio(1);                                              \
        _Pragma("unroll") for (int ks = 0; ks < 4; ++ks)                            \
            _Pragma("unroll") for (int m2 = 0; m2 < 2; ++m2)                        \
                acc[I * 2 + m2][J] = __builtin_amdgcn_mfma_f32_32x32x16_bf16(       \
                    a[m2][ks], b[ks], acc[I * 2 + m2][J], 0, 0, 0);                 \
        __builtin_amdgcn_s_setprio(0);                                              \
        __builtin_amdgcn_sched_barrier(0);                                          \
        asm volatile("s_waitcnt lgkmcnt(0)" ::: "memory");                          \
        WAIT_STMT;                                                                  \
        __builtin_amdgcn_s_barrier();                                               \
    }

template <int EPI>
__global__ __launch_bounds__(512, 2) void gemm_bt(
    const ushort* __restrict__ A, const ushort* __restrict__ B,
    void* __restrict__ Cout, const float* __restrict__ bias,
    const float* __restrict__ Y, const float* __restrict__ betaPtr,
    int M, int Ncol, int K) {
    __shared__ __align__(16) ushort lds[2][2][256 * 64];   // 128 KiB
    const int tid = threadIdx.x;
    const int wave = tid >> 6, lane = tid & 63;
    const int wm = wave >> 2, wn = wave & 3;
    const int l31 = lane & 31, lq = lane >> 5;

    // bijective XCD-aware swizzle (nwg % 8 == 0 for our launches)
    const int gx = gridDim.x;
    const int nwg = gx * gridDim.y;
    int bid = blockIdx.y * gx + blockIdx.x;
    const int qq = nwg >> 3;
    bid = (bid & 7) * qq + (bid >> 3);
    const int m0 = (bid / gx) * 256, n0 = (bid % gx) * 256;

    const ushort* Ab = A + (size_t)m0 * K;
    const ushort* Bb = B + (size_t)n0 * K;

    // precomputed swizzled LDS byte offsets for fragment reads
    int offA[2][2][4], offB[2][4];
#pragma unroll
    for (int I = 0; I < 2; ++I)
#pragma unroll
        for (int m2 = 0; m2 < 2; ++m2) {
            const int rA = wm * 128 + I * 64 + m2 * 32 + l31;
#pragma unroll
            for (int ks = 0; ks < 4; ++ks)
                offA[I][m2][ks] = (rA * 8 + ((ks * 2 + lq) ^ (rA & 7))) * 16;
        }
#pragma unroll
    for (int J = 0; J < 2; ++J) {
        const int rB = wn * 64 + J * 32 + l31;
#pragma unroll
        for (int ks = 0; ks < 4; ++ks)
            offB[J][ks] = (rB * 8 + ((ks * 2 + lq) ^ (rB & 7))) * 16;
    }

    v16f acc[4][2] = {};

    const int NT = K >> 6;

    // prologue: tile0 fully + tile1 h0; keep last halves in flight
    stage_A(Ab, lds[0][0], K, 0, 0, wave, lane);
    stage_B(Bb, lds[0][1], K, 0, 0, wave, lane);
    stage_A(Ab, lds[0][0], K, 0, 1, wave, lane);
    stage_B(Bb, lds[0][1], K, 0, 1, wave, lane);
    if (NT > 1) {
        stage_A(Ab, lds[1][0], K, 64, 0, wave, lane);
        stage_B(Bb, lds[1][1], K, 64, 0, wave, lane);
        asm volatile("s_waitcnt vmcnt(4)" ::: "memory");
    } else {
        asm volatile("s_waitcnt vmcnt(0)" ::: "memory");
    }
    __builtin_amdgcn_s_barrier();

    for (int t = 0; t < NT; ++t) {
        const int cb = t & 1, nb = cb ^ 1;
        ushort* const curA = lds[cb][0];
        ushort* const curB = lds[cb][1];
        ushort* const nxtA = lds[nb][0];
        ushort* const nxtB = lds[nb][1];
        const int kN1 = (t + 1) << 6, kN2 = (t + 2) << 6;

        PHASE(0, 0, if (t + 1 < NT) stage_A(Ab, nxtA, K, kN1, 1, wave, lane), )
        PHASE(0, 1, if (t + 1 < NT) stage_B(Bb, nxtB, K, kN1, 1, wave, lane), )
        PHASE(1, 0, if (t + 2 < NT) stage_A(Ab, curA, K, kN2, 0, wave, lane), )
        PHASE(1, 1, if (t + 2 < NT) stage_B(Bb, curB, K, kN2, 0, wave, lane),
              if (t + 2 < NT) { asm volatile("s_waitcnt vmcnt(4)" ::: "memory"); }
              else { asm volatile("s_waitcnt vmcnt(0)" ::: "memory"); })
    }

    const float betaV = (EPI == 1) ? betaPtr[0] : 0.f;
#pragma unroll
    for (int nf = 0; nf < 2; ++nf) {
        const int col = n0 + wn * 64 + nf * 32 + l31;
        const float bj = bias[col];
#pragma unroll
        for (int mf = 0; mf < 4; ++mf) {
#pragma unroll
            for (int reg = 0; reg < 16; ++reg) {
                const int row = m0 + wm * 128 + mf * 32 + (reg & 3) + 8 * (reg >> 2) + 4 * lq;
                float v = acc[mf][nf][reg] + bj;
                if (EPI == 0) {
                    v = v > 0.f ? v : 0.f;
                    ((ushort*)Cout)[(size_t)row * Ncol + col] = f32_to_bf16(v);
                } else {
                    v += betaV * Y[(size_t)row * Ncol + col];
                    ((float*)Cout)[(size_t)row * Ncol + col] = v;
                }
            }
        }
    }
    (void)M;
}

extern "C" void kernel_launch(void* const* d_in, const int* in_sizes, int n_in,
                              void* d_out, int out_size, void* d_ws, size_t ws_size,
                              hipStream_t stream) {
    const float* x    = (const float*)d_in[0];
    const float* y    = (const float*)d_in[1];
    const float* W1   = (const float*)d_in[2];
    const float* b1   = (const float*)d_in[3];
    const float* W2   = (const float*)d_in[4];
    const float* b2   = (const float*)d_in[5];
    const float* bn1g = (const float*)d_in[6];
    const float* bn1b = (const float*)d_in[7];
    const float* bn2g = (const float*)d_in[8];
    const float* bn2b = (const float*)d_in[9];
    const float* beta = (const float*)d_in[10];

    constexpr int Nb = 32768, F = 2048, H = 4096, C = 512;

    char* w = (char*)d_ws;
    ushort* xb  = (ushort*)w;                                       // 128 MB
    ushort* h1  = (ushort*)(w + (size_t)Nb * F * 2);                // 256 MB
    ushort* w1p = (ushort*)(w + (size_t)Nb * F * 2 + (size_t)Nb * H * 2);   // 16 MB
    ushort* w2p = (ushort*)((char*)w1p + (size_t)H * F * 2);        // 4 MB
    float*  fb  = (float*)((char*)w2p + (size_t)C * H * 2);
    float* b1p = fb;            // H
    float* b2p = b1p + H;       // C
    float* sum1 = b2p + C;      // F
    float* ss1  = sum1 + F;     // F
    float* s1   = ss1 + F;      // F
    float* t1   = s1 + F;       // F
    float* sum2 = t1 + F;       // H
    float* ss2  = sum2 + H;     // H
    float* s2   = ss2 + H;      // H
    float* t2   = s2 + H;       // H

    (void)hipMemsetAsync(sum1, 0, sizeof(float) * 2 * F, stream);
    (void)hipMemsetAsync(sum2, 0, sizeof(float) * 2 * H, stream);

    // BN1 stats + x->bf16 (fused)
    colstats_cvt<<<dim3(F / 4 / 256, 256), 256, 0, stream>>>(x, xb, sum1, ss1, F, Nb / 256);
    bn_finalize<<<F / 256, 256, 0, stream>>>(sum1, ss1, bn1g, bn1b, s1, t1, 1.f / Nb);
    // fold BN1 into W1
    fold_w<<<H, 256, 0, stream>>>(W1, b1, s1, t1, w1p, b1p, F);
    // h1 = relu(xb @ w1p^T + b1p), bf16
    gemm_bt<0><<<dim3(H / 256, Nb / 256), 512, 0, stream>>>(xb, w1p, h1, b1p, nullptr, nullptr, Nb, H, F);
    // BN2 stats from h1
    colstats_bf16<<<dim3(H / 2 / 256, 128), 256, 0, stream>>>(h1, sum2, ss2, H, Nb / 128);
    bn_finalize<<<H / 256, 256, 0, stream>>>(sum2, ss2, bn2g, bn2b, s2, t2, 1.f / Nb);
    // fold BN2 into W2
    fold_w<<<C, 256, 0, stream>>>(W2, b2, s2, t2, w2p, b2p, H);
    // out = h1 @ w2p^T + b2p + beta*y, fp32
    gemm_bt<1><<<dim3(C / 256, Nb / 256), 512, 0, stream>>>(h1, w2p, d_out, b2p, y, beta, Nb, C, H);
    (void)in_sizes; (void)n_in; (void)out_size; (void)ws_size;
}

// Round 4
// 1397.656 us; speedup vs baseline: 1.0129x; 1.0129x over previous
//
#include <hip/hip_runtime.h>

typedef __bf16 v8bf __attribute__((ext_vector_type(8)));
typedef float  v16f __attribute__((ext_vector_type(16)));
typedef float  f4   __attribute__((ext_vector_type(4)));
typedef unsigned int uint;
typedef unsigned short ushort;
typedef uint   v4u  __attribute__((ext_vector_type(4)));
typedef uint   v2u  __attribute__((ext_vector_type(2)));

#define GLAS(p) ((const __attribute__((address_space(1))) void*)(p))
#define LDAS(p) ((__attribute__((address_space(3))) void*)(p))

__device__ __forceinline__ ushort f32_to_bf16(float f) {
    uint u = __builtin_bit_cast(uint, f);
    uint r = u + 0x7FFFu + ((u >> 16) & 1u);   // RNE; inputs finite
    return (ushort)(r >> 16);
}
__device__ __forceinline__ float bflo(uint v) { return __builtin_bit_cast(float, v << 16); }
__device__ __forceinline__ float bfhi(uint v) { return __builtin_bit_cast(float, v & 0xFFFF0000u); }

// ---------------- fused BN1 column stats + fp32->bf16 convert ----------------
__global__ void colstats_cvt(const float* __restrict__ x, ushort* __restrict__ xb,
                             float* __restrict__ sum, float* __restrict__ ssum,
                             int ncols, int rows) {
    int c4 = blockIdx.x * blockDim.x + threadIdx.x;   // column quad index
    int q = ncols >> 2;
    size_t base = (size_t)blockIdx.y * rows * q + c4;
    const f4* x4 = (const f4*)x;
    v2u* o = (v2u*)xb;
    f4 s = {0.f, 0.f, 0.f, 0.f}, qq = {0.f, 0.f, 0.f, 0.f};
#pragma unroll 4
    for (int r = 0; r < rows; ++r) {
        f4 v = x4[base + (size_t)r * q];
        s += v; qq += v * v;
        union { ushort us[4]; v2u u; } p;
        p.us[0] = f32_to_bf16(v.x); p.us[1] = f32_to_bf16(v.y);
        p.us[2] = f32_to_bf16(v.z); p.us[3] = f32_to_bf16(v.w);
        o[base + (size_t)r * q] = p.u;
    }
    atomicAdd(&sum[4 * c4 + 0], s.x);  atomicAdd(&ssum[4 * c4 + 0], qq.x);
    atomicAdd(&sum[4 * c4 + 1], s.y);  atomicAdd(&ssum[4 * c4 + 1], qq.y);
    atomicAdd(&sum[4 * c4 + 2], s.z);  atomicAdd(&ssum[4 * c4 + 2], qq.z);
    atomicAdd(&sum[4 * c4 + 3], s.w);  atomicAdd(&ssum[4 * c4 + 3], qq.w);
}

__global__ void colstats_bf16(const ushort* __restrict__ h, float* __restrict__ sum,
                              float* __restrict__ ssum, int ncols, int rows) {
    int cp = blockIdx.x * blockDim.x + threadIdx.x;   // column pair
    int half = ncols >> 1;
    const uint* h32 = (const uint*)h;
    size_t base = (size_t)blockIdx.y * rows * half + cp;
    float s0 = 0.f, q0 = 0.f, s1 = 0.f, q1 = 0.f;
#pragma unroll 4
    for (int r = 0; r < rows; ++r) {
        uint v = h32[base + (size_t)r * half];
        float a = bflo(v), b = bfhi(v);
        s0 += a; q0 += a * a;
        s1 += b; q1 += b * b;
    }
    atomicAdd(&sum[2 * cp], s0);  atomicAdd(&ssum[2 * cp], q0);
    atomicAdd(&sum[2 * cp + 1], s1); atomicAdd(&ssum[2 * cp + 1], q1);
}

__global__ void bn_finalize(const float* __restrict__ sum, const float* __restrict__ ssum,
                            const float* __restrict__ g, const float* __restrict__ b,
                            float* __restrict__ s, float* __restrict__ t, float invN) {
    int c = blockIdx.x * blockDim.x + threadIdx.x;
    float m = sum[c] * invN;
    float var = fmaxf(ssum[c] * invN - m * m, 0.f);
    float rs = rsqrtf(var + 1e-5f);
    float sc = rs * g[c];
    s[c] = sc;
    t[c] = b[c] - m * sc;
}

// ---------------- fold BN scale/shift into weights ----------------
__global__ void fold_w(const float* __restrict__ W, const float* __restrict__ bias,
                       const float* __restrict__ s, const float* __restrict__ t,
                       ushort* __restrict__ Wp, float* __restrict__ bp, int K) {
    int j = blockIdx.x, tx = threadIdx.x;
    const f4* row = (const f4*)(W + (size_t)j * K);
    const f4* s4 = (const f4*)s;
    const f4* t4 = (const f4*)t;
    v2u* orow = (v2u*)(Wp + (size_t)j * K);
    float part = 0.f;
    int K4 = K >> 2;
    for (int k = tx; k < K4; k += 256) {
        f4 v = row[k], sv = s4[k], tv = t4[k];
        part += v.x * tv.x + v.y * tv.y + v.z * tv.z + v.w * tv.w;
        union { ushort us[4]; v2u u; } o;
        o.us[0] = f32_to_bf16(v.x * sv.x);
        o.us[1] = f32_to_bf16(v.y * sv.y);
        o.us[2] = f32_to_bf16(v.z * sv.z);
        o.us[3] = f32_to_bf16(v.w * sv.w);
        orow[k] = o.u;
    }
    __shared__ float red[256];
    red[tx] = part;
    __syncthreads();
    for (int off = 128; off > 0; off >>= 1) {
        if (tx < off) red[tx] += red[tx + off];
        __syncthreads();
    }
    if (tx == 0) bp[j] = bias[j] + red[0];
}

// ---------------- 256x256 8-phase bf16 MFMA GEMM (B^T layout) ----------------
// C[m,n] = sum_k A[m,k]*B[n,k] (+ epilogue).  BM=BN=256, BK=64, 512 threads =
// 8 waves (2M x 4N); each wave owns 128x64 via 4x2 frags of 32x32x16 MFMA.
// LDS: 2 dbuf x (A,B) x 256x64 bf16 = 128 KiB.  Granule (row,c) (granule = 8
// bf16 = 16B) lives at physical granule row*8 + (c ^ (row&7)).
// Per K-tile: 4 quadrant phases (i,j) in {(0,0),(0,1),(1,0),(1,1)}:
//   12 ds_read_b128 || stage one half-tile (2 global_load_lds/wave)
//   s_barrier; setprio(1); 8 MFMA (compiler-counted lgkm waits -- NO forced
//   drain / sched_barrier: the fine ds_read||MFMA interleave IS the lever,
//   m196); setprio(0); [boundary vmcnt, "memory"]; s_barrier
// Safety without per-phase lgkmcnt(0): every ds_read value is consumed by an
// MFMA in the same phase, so operands are in registers before the wave passes
// the closing barrier, which precedes any overwriting stage's issue; the
// cross-iteration buffer reuse is fenced by the clobbered vmcnt(4)+barrier.
// Staging runs 1.5 tiles ahead into just-freed regions:
//   ph0: (t+1).A-h1 -> nxt   ph1: (t+1).B-h1 -> nxt
//   ph2: (t+2).A-h0 -> cur   ph3: (t+2).B-h0 -> cur
// Boundary vmcnt(4) at ph3 => tile t+1 (oldest loads) landed; 2 half-tiles of
// tile t+2 stay in flight across the barrier (never drain to 0 == T4).
// 32x32x16 A/B frag: m(or n)=lane&31, k=(lane>>5)*8+j.
// 32x32 C/D: col=lane&31, row=(reg&3)+8*(reg>>2)+4*(lane>>5)   [m74/m101]
// EPI=0: out bf16 = relu(acc + bias[col]);  EPI=1: f32 = acc+bias+beta*Y.

__device__ __forceinline__ void stage_A(const ushort* __restrict__ Mat, ushort* dst,
                                        int K, int k0, int ihalf, int wave, int lane) {
    const int rs = lane >> 3;
    const int gc = (lane & 7) ^ rs;
    const int rb0 = ihalf * 64 + wave * 8;
    const int rb1 = rb0 + 128;
    const ushort* s0 = Mat + (size_t)(rb0 + rs) * K + k0 + gc * 8;
    const ushort* s1 = Mat + (size_t)(rb1 + rs) * K + k0 + gc * 8;
    __builtin_amdgcn_global_load_lds(GLAS(s0), LDAS(dst + rb0 * 64), 16, 0, 0);
    __builtin_amdgcn_global_load_lds(GLAS(s1), LDAS(dst + rb1 * 64), 16, 0, 0);
}
__device__ __forceinline__ void stage_B(const ushort* __restrict__ Mat, ushort* dst,
                                        int K, int k0, int jhalf, int wave, int lane) {
    const int rs = lane >> 3;
    const int gc = (lane & 7) ^ rs;
    const int rb0 = (wave >> 2) * 64 + jhalf * 32 + (wave & 3) * 8;
    const int rb1 = rb0 + 128;
    const ushort* s0 = Mat + (size_t)(rb0 + rs) * K + k0 + gc * 8;
    const ushort* s1 = Mat + (size_t)(rb1 + rs) * K + k0 + gc * 8;
    __builtin_amdgcn_global_load_lds(GLAS(s0), LDAS(dst + rb0 * 64), 16, 0, 0);
    __builtin_amdgcn_global_load_lds(GLAS(s1), LDAS(dst + rb1 * 64), 16, 0, 0);
}

#define PHASE(I, J, STAGE_STMT, WAIT_STMT)                                          \
    {                                                                               \
        v8bf a[2][4], b[4];                                                         \
        _Pragma("unroll") for (int m2 = 0; m2 < 2; ++m2)                            \
            _Pragma("unroll") for (int ks = 0; ks < 4; ++ks)                        \
                a[m2][ks] = __builtin_bit_cast(                                     \
                    v8bf, *(const v4u*)((const char*)curA + offA[I][m2][ks]));      \
        _Pragma("unroll") for (int ks = 0; ks < 4; ++ks)                            \
            b[ks] = __builtin_bit_cast(                                             \
                v8bf, *(const v4u*)((const char*)curB + offB[J][ks]));              \
        STAGE_STMT;                                                                 \
        __builtin_amdgcn_s_barrier();                                               \
        __builtin_amdgcn_s_setprio(1);                                              \
        _Pragma("unroll") for (int ks = 0; ks < 4; ++ks)                            \
            _Pragma("unroll") for (int m2 = 0; m2 < 2; ++m2)                        \
                acc[I * 2 + m2][J] = __builtin_amdgcn_mfma_f32_32x32x16_bf16(       \
                    a[m2][ks], b[ks], acc[I * 2 + m2][J], 0, 0, 0);                 \
        __builtin_amdgcn_s_setprio(0);                                              \
        WAIT_STMT;                                                                  \
        __builtin_amdgcn_s_barrier();                                               \
    }

template <int EPI>
__global__ __launch_bounds__(512, 2) void gemm_bt(
    const ushort* __restrict__ A, const ushort* __restrict__ B,
    void* __restrict__ Cout, const float* __restrict__ bias,
    const float* __restrict__ Y, const float* __restrict__ betaPtr,
    int M, int Ncol, int K) {
    __shared__ __align__(16) ushort lds[2][2][256 * 64];   // 128 KiB
    const int tid = threadIdx.x;
    const int wave = tid >> 6, lane = tid & 63;
    const int wm = wave >> 2, wn = wave & 3;
    const int l31 = lane & 31, lq = lane >> 5;

    // bijective XCD-aware swizzle (nwg % 8 == 0 for our launches)
    const int gx = gridDim.x;
    const int nwg = gx * gridDim.y;
    int bid = blockIdx.y * gx + blockIdx.x;
    const int qq = nwg >> 3;
    bid = (bid & 7) * qq + (bid >> 3);
    const int m0 = (bid / gx) * 256, n0 = (bid % gx) * 256;

    const ushort* Ab = A + (size_t)m0 * K;
    const ushort* Bb = B + (size_t)n0 * K;

    // precomputed swizzled LDS byte offsets for fragment reads
    int offA[2][2][4], offB[2][4];
#pragma unroll
    for (int I = 0; I < 2; ++I)
#pragma unroll
        for (int m2 = 0; m2 < 2; ++m2) {
            const int rA = wm * 128 + I * 64 + m2 * 32 + l31;
#pragma unroll
            for (int ks = 0; ks < 4; ++ks)
                offA[I][m2][ks] = (rA * 8 + ((ks * 2 + lq) ^ (rA & 7))) * 16;
        }
#pragma unroll
    for (int J = 0; J < 2; ++J) {
        const int rB = wn * 64 + J * 32 + l31;
#pragma unroll
        for (int ks = 0; ks < 4; ++ks)
            offB[J][ks] = (rB * 8 + ((ks * 2 + lq) ^ (rB & 7))) * 16;
    }

    v16f acc[4][2] = {};

    const int NT = K >> 6;

    // prologue: tile0 fully + tile1 h0; keep last halves in flight
    stage_A(Ab, lds[0][0], K, 0, 0, wave, lane);
    stage_B(Bb, lds[0][1], K, 0, 0, wave, lane);
    stage_A(Ab, lds[0][0], K, 0, 1, wave, lane);
    stage_B(Bb, lds[0][1], K, 0, 1, wave, lane);
    if (NT > 1) {
        stage_A(Ab, lds[1][0], K, 64, 0, wave, lane);
        stage_B(Bb, lds[1][1], K, 64, 0, wave, lane);
        asm volatile("s_waitcnt vmcnt(4)" ::: "memory");
    } else {
        asm volatile("s_waitcnt vmcnt(0)" ::: "memory");
    }
    __builtin_amdgcn_s_barrier();

    for (int t = 0; t < NT; ++t) {
        const int cb = t & 1, nb = cb ^ 1;
        ushort* const curA = lds[cb][0];
        ushort* const curB = lds[cb][1];
        ushort* const nxtA = lds[nb][0];
        ushort* const nxtB = lds[nb][1];
        const int kN1 = (t + 1) << 6, kN2 = (t + 2) << 6;

        PHASE(0, 0, if (t + 1 < NT) stage_A(Ab, nxtA, K, kN1, 1, wave, lane), )
        PHASE(0, 1, if (t + 1 < NT) stage_B(Bb, nxtB, K, kN1, 1, wave, lane), )
        PHASE(1, 0, if (t + 2 < NT) stage_A(Ab, curA, K, kN2, 0, wave, lane), )
        PHASE(1, 1, if (t + 2 < NT) stage_B(Bb, curB, K, kN2, 0, wave, lane),
              if (t + 2 < NT) { asm volatile("s_waitcnt vmcnt(4)" ::: "memory"); }
              else { asm volatile("s_waitcnt vmcnt(0)" ::: "memory"); })
    }

    const float betaV = (EPI == 1) ? betaPtr[0] : 0.f;
#pragma unroll
    for (int nf = 0; nf < 2; ++nf) {
        const int col = n0 + wn * 64 + nf * 32 + l31;
        const float bj = bias[col];
#pragma unroll
        for (int mf = 0; mf < 4; ++mf) {
#pragma unroll
            for (int reg = 0; reg < 16; ++reg) {
                const int row = m0 + wm * 128 + mf * 32 + (reg & 3) + 8 * (reg >> 2) + 4 * lq;
                float v = acc[mf][nf][reg] + bj;
                if (EPI == 0) {
                    v = v > 0.f ? v : 0.f;
                    ((ushort*)Cout)[(size_t)row * Ncol + col] = f32_to_bf16(v);
                } else {
                    v += betaV * Y[(size_t)row * Ncol + col];
                    ((float*)Cout)[(size_t)row * Ncol + col] = v;
                }
            }
        }
    }
    (void)M;
}

extern "C" void kernel_launch(void* const* d_in, const int* in_sizes, int n_in,
                              void* d_out, int out_size, void* d_ws, size_t ws_size,
                              hipStream_t stream) {
    const float* x    = (const float*)d_in[0];
    const float* y    = (const float*)d_in[1];
    const float* W1   = (const float*)d_in[2];
    const float* b1   = (const float*)d_in[3];
    const float* W2   = (const float*)d_in[4];
    const float* b2   = (const float*)d_in[5];
    const float* bn1g = (const float*)d_in[6];
    const float* bn1b = (const float*)d_in[7];
    const float* bn2g = (const float*)d_in[8];
    const float* bn2b = (const float*)d_in[9];
    const float* beta = (const float*)d_in[10];

    constexpr int Nb = 32768, F = 2048, H = 4096, C = 512;

    char* w = (char*)d_ws;
    ushort* xb  = (ushort*)w;                                       // 128 MB
    ushort* h1  = (ushort*)(w + (size_t)Nb * F * 2);                // 256 MB
    ushort* w1p = (ushort*)(w + (size_t)Nb * F * 2 + (size_t)Nb * H * 2);   // 16 MB
    ushort* w2p = (ushort*)((char*)w1p + (size_t)H * F * 2);        // 4 MB
    float*  fb  = (float*)((char*)w2p + (size_t)C * H * 2);
    float* b1p = fb;            // H
    float* b2p = b1p + H;       // C
    float* sum1 = b2p + C;      // F
    float* ss1  = sum1 + F;     // F
    float* s1   = ss1 + F;      // F
    float* t1   = s1 + F;       // F
    float* sum2 = t1 + F;       // H
    float* ss2  = sum2 + H;     // H
    float* s2   = ss2 + H;      // H
    float* t2   = s2 + H;       // H

    (void)hipMemsetAsync(sum1, 0, sizeof(float) * 2 * F, stream);
    (void)hipMemsetAsync(sum2, 0, sizeof(float) * 2 * H, stream);

    // BN1 stats + x->bf16 (fused)
    colstats_cvt<<<dim3(F / 4 / 256, 256), 256, 0, stream>>>(x, xb, sum1, ss1, F, Nb / 256);
    bn_finalize<<<F / 256, 256, 0, stream>>>(sum1, ss1, bn1g, bn1b, s1, t1, 1.f / Nb);
    // fold BN1 into W1
    fold_w<<<H, 256, 0, stream>>>(W1, b1, s1, t1, w1p, b1p, F);
    // h1 = relu(xb @ w1p^T + b1p), bf16
    gemm_bt<0><<<dim3(H / 256, Nb / 256), 512, 0, stream>>>(xb, w1p, h1, b1p, nullptr, nullptr, Nb, H, F);
    // BN2 stats from h1
    colstats_bf16<<<dim3(H / 2 / 256, 128), 256, 0, stream>>>(h1, sum2, ss2, H, Nb / 128);
    bn_finalize<<<H / 256, 256, 0, stream>>>(sum2, ss2, bn2g, bn2b, s2, t2, 1.f / Nb);
    // fold BN2 into W2
    fold_w<<<C, 256, 0, stream>>>(W2, b2, s2, t2, w2p, b2p, H);
    // out = h1 @ w2p^T + b2p + beta*y, fp32
    gemm_bt<1><<<dim3(C / 256, Nb / 256), 512, 0, stream>>>(h1, w2p, d_out, b2p, y, beta, Nb, C, H);
    (void)in_sizes; (void)n_in; (void)out_size; (void)ws_size;
}

// Round 5
// 1264.379 us; speedup vs baseline: 1.1197x; 1.1054x over previous
//
#include <hip/hip_runtime.h>

typedef __bf16 v8bf __attribute__((ext_vector_type(8)));
typedef float  f4   __attribute__((ext_vector_type(4)));
typedef unsigned int uint;
typedef unsigned short ushort;
typedef uint   v4u  __attribute__((ext_vector_type(4)));
typedef uint   v2u  __attribute__((ext_vector_type(2)));

#define GLAS(p) ((const __attribute__((address_space(1))) void*)(p))
#define LDAS(p) ((__attribute__((address_space(3))) void*)(p))

__device__ __forceinline__ ushort f32_to_bf16(float f) {
    uint u = __builtin_bit_cast(uint, f);
    uint r = u + 0x7FFFu + ((u >> 16) & 1u);   // RNE; inputs finite
    return (ushort)(r >> 16);
}
__device__ __forceinline__ float bflo(uint v) { return __builtin_bit_cast(float, v << 16); }
__device__ __forceinline__ float bfhi(uint v) { return __builtin_bit_cast(float, v & 0xFFFF0000u); }

// ---------------- fused BN1 column stats + fp32->bf16 convert ----------------
__global__ void colstats_cvt(const float* __restrict__ x, ushort* __restrict__ xb,
                             float* __restrict__ sum, float* __restrict__ ssum,
                             int ncols, int rows) {
    int c4 = blockIdx.x * blockDim.x + threadIdx.x;   // column quad index
    int q = ncols >> 2;
    size_t base = (size_t)blockIdx.y * rows * q + c4;
    const f4* x4 = (const f4*)x;
    v2u* o = (v2u*)xb;
    f4 s = {0.f, 0.f, 0.f, 0.f}, qq = {0.f, 0.f, 0.f, 0.f};
#pragma unroll 4
    for (int r = 0; r < rows; ++r) {
        f4 v = x4[base + (size_t)r * q];
        s += v; qq += v * v;
        union { ushort us[4]; v2u u; } p;
        p.us[0] = f32_to_bf16(v.x); p.us[1] = f32_to_bf16(v.y);
        p.us[2] = f32_to_bf16(v.z); p.us[3] = f32_to_bf16(v.w);
        o[base + (size_t)r * q] = p.u;
    }
    atomicAdd(&sum[4 * c4 + 0], s.x);  atomicAdd(&ssum[4 * c4 + 0], qq.x);
    atomicAdd(&sum[4 * c4 + 1], s.y);  atomicAdd(&ssum[4 * c4 + 1], qq.y);
    atomicAdd(&sum[4 * c4 + 2], s.z);  atomicAdd(&ssum[4 * c4 + 2], qq.z);
    atomicAdd(&sum[4 * c4 + 3], s.w);  atomicAdd(&ssum[4 * c4 + 3], qq.w);
}

__global__ void colstats_bf16(const ushort* __restrict__ h, float* __restrict__ sum,
                              float* __restrict__ ssum, int ncols, int rows) {
    int cp = blockIdx.x * blockDim.x + threadIdx.x;   // column pair
    int half = ncols >> 1;
    const uint* h32 = (const uint*)h;
    size_t base = (size_t)blockIdx.y * rows * half + cp;
    float s0 = 0.f, q0 = 0.f, s1 = 0.f, q1 = 0.f;
#pragma unroll 4
    for (int r = 0; r < rows; ++r) {
        uint v = h32[base + (size_t)r * half];
        float a = bflo(v), b = bfhi(v);
        s0 += a; q0 += a * a;
        s1 += b; q1 += b * b;
    }
    atomicAdd(&sum[2 * cp], s0);  atomicAdd(&ssum[2 * cp], q0);
    atomicAdd(&sum[2 * cp + 1], s1); atomicAdd(&ssum[2 * cp + 1], q1);
}

__global__ void bn_finalize(const float* __restrict__ sum, const float* __restrict__ ssum,
                            const float* __restrict__ g, const float* __restrict__ b,
                            float* __restrict__ s, float* __restrict__ t, float invN) {
    int c = blockIdx.x * blockDim.x + threadIdx.x;
    float m = sum[c] * invN;
    float var = fmaxf(ssum[c] * invN - m * m, 0.f);
    float rs = rsqrtf(var + 1e-5f);
    float sc = rs * g[c];
    s[c] = sc;
    t[c] = b[c] - m * sc;
}

// ---------------- fold BN scale/shift into weights ----------------
__global__ void fold_w(const float* __restrict__ W, const float* __restrict__ bias,
                       const float* __restrict__ s, const float* __restrict__ t,
                       ushort* __restrict__ Wp, float* __restrict__ bp, int K) {
    int j = blockIdx.x, tx = threadIdx.x;
    const f4* row = (const f4*)(W + (size_t)j * K);
    const f4* s4 = (const f4*)s;
    const f4* t4 = (const f4*)t;
    v2u* orow = (v2u*)(Wp + (size_t)j * K);
    float part = 0.f;
    int K4 = K >> 2;
    for (int k = tx; k < K4; k += 256) {
        f4 v = row[k], sv = s4[k], tv = t4[k];
        part += v.x * tv.x + v.y * tv.y + v.z * tv.z + v.w * tv.w;
        union { ushort us[4]; v2u u; } o;
        o.us[0] = f32_to_bf16(v.x * sv.x);
        o.us[1] = f32_to_bf16(v.y * sv.y);
        o.us[2] = f32_to_bf16(v.z * sv.z);
        o.us[3] = f32_to_bf16(v.w * sv.w);
        orow[k] = o.u;
    }
    __shared__ float red[256];
    red[tx] = part;
    __syncthreads();
    for (int off = 128; off > 0; off >>= 1) {
        if (tx < off) red[tx] += red[tx + off];
        __syncthreads();
    }
    if (tx == 0) bp[j] = bias[j] + red[0];
}

// ------------- 256x256 8-phase bf16 MFMA GEMM, m201 configuration -------------
// C[m,n] = sum_k A[m,k]*B[n,k] (+ epilogue).  BM=BN=256, BK=64, 512 threads =
// 8 waves (2M x 4N); wave owns 128x64 out via 8x4 frags of 16x16x32 MFMA.
// LDS: 2 dbuf x 4 regions [128 rows][64 bf16] (16KB each) = 128 KiB:
//   Ah_I = A rows {wm*128 + I*64 + 0..63}  (region row rr = wm*64 + r)
//   Bh_J = B rows {wn*64 + J*32 + 0..31}   (region row rr = wn*32 + r)
// st_16x32 swizzle [T2, m201]: phys col_byte = logical ^ ((rr>>2)&1)<<5;
// staged via global_load_lds w16 with inverse-swizzled (same XOR) global src,
// linear LDS dest (wave-uniform base + lane*16).
// Per K-tile, 4 quadrant phases with operand reuse (reads 12/4/8/4):
//   ph0 Q(0,0): rd A<-Ah0, B<-Bh0 | stage (t+1).Ah1->nxt | bar|prio|16 MFMA|bar
//   ph1 Q(0,1): rd B<-Bh1 (A reused) | stage (t+1).Bh0->nxt | ...
//   ph2 Q(1,1): rd A<-Ah1 (B reused) | stage (t+2).Ah0->cur (dead after ph1)
//   ph3 Q(1,0): rd B<-Bh0 (A reused) | stage (t+2).Bh1->cur (dead after ph2)
//   boundary: vmcnt(4) (keep (t+2).Ah0/Bh1 = 4 loads in flight; never 0 == T4)
// Retire audit: outstanding at boundary (oldest first) = [t+1.Ah0, t+1.Bh1,
// t+1.Ah1, t+1.Bh0, t+2.Ah0, t+2.Bh1] (12); vmcnt(4) retires all of t+1.  WAR:
// region writes issued >=2 barriers after that region's last ds_read completed.
// Tail: boundary vmcnt(0) when t+2>=NT.
// 16x16x32 frag: m(n)=lane&15, k=(lane>>4)*8+j. C/D: col=lane&15,
// row=(lane>>4)*4+reg  [m89/m91].
// EPI=0: out bf16 = relu(acc + bias[col]);  EPI=1: f32 = acc+bias+beta*Y.

__device__ __forceinline__ void stageA(const ushort* __restrict__ Mat, ushort* dstRegion,
                                       int K, int k0, int I, int wave, int lane) {
#pragma unroll
    for (int h = 0; h < 2; ++h) {
        const int rrb = h * 64 + wave * 8;
        const int rr  = rrb + (lane >> 3);
        const int cp  = (lane & 7) << 4;
        const int gc  = cp ^ (((rr >> 2) & 1) << 5);
        const int grow = (rr & 63) + ((rr >> 6) << 7) + I * 64;
        const ushort* src = Mat + (size_t)grow * K + k0 + (gc >> 1);
        __builtin_amdgcn_global_load_lds(GLAS(src), LDAS(dstRegion + rrb * 64), 16, 0, 0);
    }
}
__device__ __forceinline__ void stageB(const ushort* __restrict__ Mat, ushort* dstRegion,
                                       int K, int k0, int J, int wave, int lane) {
#pragma unroll
    for (int h = 0; h < 2; ++h) {
        const int rrb = h * 64 + wave * 8;
        const int rr  = rrb + (lane >> 3);
        const int cp  = (lane & 7) << 4;
        const int gc  = cp ^ (((rr >> 2) & 1) << 5);
        const int gn  = (rr & 31) + ((rr >> 5) << 6) + J * 32;
        const ushort* src = Mat + (size_t)gn * K + k0 + (gc >> 1);
        __builtin_amdgcn_global_load_lds(GLAS(src), LDAS(dstRegion + rrb * 64), 16, 0, 0);
    }
}

#define RD_A(rg)                                                                    \
    _Pragma("unroll") for (int mf = 0; mf < 4; ++mf)                                \
        _Pragma("unroll") for (int ks = 0; ks < 2; ++ks)                            \
            a[mf][ks] = __builtin_bit_cast(                                         \
                v8bf, *(const v4u*)((const char*)(rg) + offA[mf][ks]));

#define RD_B(rg)                                                                    \
    _Pragma("unroll") for (int nf = 0; nf < 2; ++nf)                                \
        _Pragma("unroll") for (int ks = 0; ks < 2; ++ks)                            \
            b[nf][ks] = __builtin_bit_cast(                                         \
                v8bf, *(const v4u*)((const char*)(rg) + offB[nf][ks]));

#define MM(I, J)                                                                    \
    __builtin_amdgcn_s_barrier();                                                   \
    __builtin_amdgcn_s_setprio(1);                                                  \
    _Pragma("unroll") for (int ks = 0; ks < 2; ++ks)                                \
        _Pragma("unroll") for (int mf = 0; mf < 4; ++mf)                            \
            _Pragma("unroll") for (int nf = 0; nf < 2; ++nf)                        \
                acc[(I) * 4 + mf][(J) * 2 + nf] =                                   \
                    __builtin_amdgcn_mfma_f32_16x16x32_bf16(                        \
                        a[mf][ks], b[nf][ks], acc[(I) * 4 + mf][(J) * 2 + nf],      \
                        0, 0, 0);                                                   \
    __builtin_amdgcn_s_setprio(0);

template <int EPI>
__global__ __launch_bounds__(512, 2) void gemm_bt(
    const ushort* __restrict__ A, const ushort* __restrict__ B,
    void* __restrict__ Cout, const float* __restrict__ bias,
    const float* __restrict__ Y, const float* __restrict__ betaPtr,
    int M, int Ncol, int K) {
    __shared__ __align__(16) ushort lds[2][4][128 * 64];   // [buf][Ah0,Ah1,Bh0,Bh1]
    const int tid = threadIdx.x;
    const int wave = tid >> 6, lane = tid & 63;
    const int wm = wave >> 2, wn = wave & 3;
    const int l15 = lane & 15, l4 = lane >> 4;

    // bijective XCD-aware swizzle (nwg % 8 == 0 for our launches)
    const int gx = gridDim.x;
    const int nwg = gx * gridDim.y;
    int bid = blockIdx.y * gx + blockIdx.x;
    const int qq = nwg >> 3;
    bid = (bid & 7) * qq + (bid >> 3);
    const int m0 = (bid / gx) * 256, n0 = (bid % gx) * 256;

    const ushort* Ab = A + (size_t)m0 * K;
    const ushort* Bb = B + (size_t)n0 * K;

    // per-thread swizzled read byte-offsets within a 16KB region
    int offA[4][2], offB[2][2];
#pragma unroll
    for (int mf = 0; mf < 4; ++mf) {
        const int rr = wm * 64 + mf * 16 + l15;
        const int sw = ((rr >> 2) & 1) << 5;
#pragma unroll
        for (int ks = 0; ks < 2; ++ks)
            offA[mf][ks] = rr * 128 + ((ks * 64 + l4 * 16) ^ sw);
    }
#pragma unroll
    for (int nf = 0; nf < 2; ++nf) {
        const int rr = wn * 32 + nf * 16 + l15;
        const int sw = ((rr >> 2) & 1) << 5;
#pragma unroll
        for (int ks = 0; ks < 2; ++ks)
            offB[nf][ks] = rr * 128 + ((ks * 64 + l4 * 16) ^ sw);
    }

    f4 acc[8][4] = {};
    v8bf a[4][2], b[2][2];

    const int NT = K >> 6;

    // prologue: all of tile0 (8 loads), then tile1.Ah0 + tile1.Bh1 (4 loads)
    stageA(Ab, lds[0][0], K, 0, 0, wave, lane);
    stageA(Ab, lds[0][1], K, 0, 1, wave, lane);
    stageB(Bb, lds[0][2], K, 0, 0, wave, lane);
    stageB(Bb, lds[0][3], K, 0, 1, wave, lane);
    if (NT > 1) {
        stageA(Ab, lds[1][0], K, 64, 0, wave, lane);
        stageB(Bb, lds[1][3], K, 64, 1, wave, lane);
        asm volatile("s_waitcnt vmcnt(4)" ::: "memory");
    } else {
        asm volatile("s_waitcnt vmcnt(0)" ::: "memory");
    }
    __builtin_amdgcn_s_barrier();

    for (int t = 0; t < NT; ++t) {
        const int cb = t & 1, nb = cb ^ 1;
        const int kN1 = (t + 1) << 6, kN2 = (t + 2) << 6;

        // ph0: Q(0,0)
        RD_A(lds[cb][0]);
        RD_B(lds[cb][2]);
        if (t + 1 < NT) stageA(Ab, lds[nb][1], K, kN1, 1, wave, lane);
        MM(0, 0);
        __builtin_amdgcn_s_barrier();

        // ph1: Q(0,1) — A reused
        RD_B(lds[cb][3]);
        if (t + 1 < NT) stageB(Bb, lds[nb][2], K, kN1, 0, wave, lane);
        MM(0, 1);
        __builtin_amdgcn_s_barrier();

        // ph2: Q(1,1) — B reused; recycle cur.Ah0 (dead after ph1)
        RD_A(lds[cb][1]);
        if (t + 2 < NT) stageA(Ab, lds[cb][0], K, kN2, 0, wave, lane);
        MM(1, 1);
        __builtin_amdgcn_s_barrier();

        // ph3: Q(1,0) — A reused; recycle cur.Bh1 (dead after ph2)
        RD_B(lds[cb][2]);
        if (t + 2 < NT) stageB(Bb, lds[cb][3], K, kN2, 1, wave, lane);
        MM(1, 0);
        if (t + 2 < NT) { asm volatile("s_waitcnt vmcnt(4)" ::: "memory"); }
        else            { asm volatile("s_waitcnt vmcnt(0)" ::: "memory"); }
        __builtin_amdgcn_s_barrier();
    }

    const float betaV = (EPI == 1) ? betaPtr[0] : 0.f;
#pragma unroll
    for (int Nf = 0; Nf < 4; ++Nf) {
        const int col = n0 + wn * 64 + Nf * 16 + l15;
        const float bj = bias[col];
#pragma unroll
        for (int Mf = 0; Mf < 8; ++Mf) {
#pragma unroll
            for (int reg = 0; reg < 4; ++reg) {
                const int row = m0 + wm * 128 + Mf * 16 + l4 * 4 + reg;
                float v = acc[Mf][Nf][reg] + bj;
                if (EPI == 0) {
                    v = v > 0.f ? v : 0.f;
                    ((ushort*)Cout)[(size_t)row * Ncol + col] = f32_to_bf16(v);
                } else {
                    v += betaV * Y[(size_t)row * Ncol + col];
                    ((float*)Cout)[(size_t)row * Ncol + col] = v;
                }
            }
        }
    }
    (void)M;
}

extern "C" void kernel_launch(void* const* d_in, const int* in_sizes, int n_in,
                              void* d_out, int out_size, void* d_ws, size_t ws_size,
                              hipStream_t stream) {
    const float* x    = (const float*)d_in[0];
    const float* y    = (const float*)d_in[1];
    const float* W1   = (const float*)d_in[2];
    const float* b1   = (const float*)d_in[3];
    const float* W2   = (const float*)d_in[4];
    const float* b2   = (const float*)d_in[5];
    const float* bn1g = (const float*)d_in[6];
    const float* bn1b = (const float*)d_in[7];
    const float* bn2g = (const float*)d_in[8];
    const float* bn2b = (const float*)d_in[9];
    const float* beta = (const float*)d_in[10];

    constexpr int Nb = 32768, F = 2048, H = 4096, C = 512;

    char* w = (char*)d_ws;
    ushort* xb  = (ushort*)w;                                       // 128 MB
    ushort* h1  = (ushort*)(w + (size_t)Nb * F * 2);                // 256 MB
    ushort* w1p = (ushort*)(w + (size_t)Nb * F * 2 + (size_t)Nb * H * 2);   // 16 MB
    ushort* w2p = (ushort*)((char*)w1p + (size_t)H * F * 2);        // 4 MB
    float*  fb  = (float*)((char*)w2p + (size_t)C * H * 2);
    float* b1p = fb;            // H
    float* b2p = b1p + H;       // C
    float* sum1 = b2p + C;      // F
    float* ss1  = sum1 + F;     // F
    float* s1   = ss1 + F;      // F
    float* t1   = s1 + F;       // F
    float* sum2 = t1 + F;       // H
    float* ss2  = sum2 + H;     // H
    float* s2   = ss2 + H;      // H
    float* t2   = s2 + H;       // H

    (void)hipMemsetAsync(sum1, 0, sizeof(float) * 2 * F, stream);
    (void)hipMemsetAsync(sum2, 0, sizeof(float) * 2 * H, stream);

    // BN1 stats + x->bf16 (fused)
    colstats_cvt<<<dim3(F / 4 / 256, 256), 256, 0, stream>>>(x, xb, sum1, ss1, F, Nb / 256);
    bn_finalize<<<F / 256, 256, 0, stream>>>(sum1, ss1, bn1g, bn1b, s1, t1, 1.f / Nb);
    // fold BN1 into W1
    fold_w<<<H, 256, 0, stream>>>(W1, b1, s1, t1, w1p, b1p, F);
    // h1 = relu(xb @ w1p^T + b1p), bf16
    gemm_bt<0><<<dim3(H / 256, Nb / 256), 512, 0, stream>>>(xb, w1p, h1, b1p, nullptr, nullptr, Nb, H, F);
    // BN2 stats from h1
    colstats_bf16<<<dim3(H / 2 / 256, 128), 256, 0, stream>>>(h1, sum2, ss2, H, Nb / 128);
    bn_finalize<<<H / 256, 256, 0, stream>>>(sum2, ss2, bn2g, bn2b, s2, t2, 1.f / Nb);
    // fold BN2 into W2
    fold_w<<<C, 256, 0, stream>>>(W2, b2, s2, t2, w2p, b2p, H);
    // out = h1 @ w2p^T + b2p + beta*y, fp32
    gemm_bt<1><<<dim3(C / 256, Nb / 256), 512, 0, stream>>>(h1, w2p, d_out, b2p, y, beta, Nb, C, H);
    (void)in_sizes; (void)n_in; (void)out_size; (void)ws_size;
}